// Round 2
// baseline (158.615 us; speedup 1.0000x reference)
//
#include <hip/hip_runtime.h>

#define EPV    0.0001f
#define EPMAXV 30.0f
#define RTOLV  1e-5f
#define ATOLV  1e-8f
#define CHUNK  64
#define MAIN_GRID 2048

// ---------------------------------------------------------------------------
// ws layout:
//   [0,8)   double acc
//   [8,12)  uint   pair count
//   [16, 16+8*cap)           int2 pairs
//   [16+8*cap, ...)          float pF[(L+cap)*12]   (pred frames: 3x3 rot rows + tran)
//   then                     float tF[(L+cap)*12]   (target frames)
// ---------------------------------------------------------------------------

// one block per row; each thread scans 4 consecutive columns (int4), no int div
__global__ void k_pairs(const int* __restrict__ m, int L, int2* __restrict__ pairs,
                        unsigned int* __restrict__ count, int cap) {
    int i = blockIdx.x;
    const int* row = m + (size_t)i * L;
    int L4 = L >> 2;                       // L assumed multiple of 4 (1024); tail below
    for (int t = threadIdx.x; t < L4; t += 256) {
        int4 v = ((const int4*)row)[t];
        int j = t * 4;
#pragma unroll
        for (int k = 0; k < 4; k++) {
            int vk = (k == 0) ? v.x : (k == 1) ? v.y : (k == 2) ? v.z : v.w;
            int jj = j + k;
            if (jj > i && vk == 1) {
                unsigned int pos = atomicAdd(count, 1u);
                if (pos < (unsigned int)cap) pairs[pos] = make_int2(i, jj);
            }
        }
    }
    for (int jj = (L4 << 2) + threadIdx.x; jj < L; jj += 256) {
        if (jj > i && row[jj] == 1) {
            unsigned int pos = atomicAdd(count, 1u);
            if (pos < (unsigned int)cap) pairs[pos] = make_int2(i, jj);
        }
    }
}

__global__ void k_base(const float* __restrict__ rot, const float* __restrict__ trans,
                       const float* __restrict__ target, int L,
                       float* __restrict__ pF, float* __restrict__ tF) {
    int l = blockIdx.x * 256 + threadIdx.x;
    if (l >= L) return;
    float* pf = pF + l * 12;
#pragma unroll
    for (int k = 0; k < 9; k++) pf[k] = rot[l * 9 + k];
    pf[9]  = trans[l * 3 + 0];
    pf[10] = trans[l * 3 + 1];
    pf[11] = trans[l * 3 + 2];
    const float* tg = target + l * 9;
    float x1x = tg[0], x1y = tg[1], x1z = tg[2];
    float x2x = tg[3], x2y = tg[4], x2z = tg[5];
    float x3x = tg[6], x3y = tg[7], x3z = tg[8];
    float v1x = x3x - x2x, v1y = x3y - x2y, v1z = x3z - x2z;
    float v2x = x1x - x2x, v2y = x1y - x2y, v2z = x1z - x2z;
    float n1 = sqrtf(v1x * v1x + v1y * v1y + v1z * v1z) + 0.001f;
    float e1x = v1x / n1, e1y = v1y / n1, e1z = v1z / n1;
    float c = e1x * v2x + e1y * v2y + e1z * v2z;
    float u2x = v2x - c * e1x, u2y = v2y - c * e1y, u2z = v2z - c * e1z;
    float n2 = sqrtf(u2x * u2x + u2y * u2y + u2z * u2z) + 1e-8f;
    float e2x = u2x / n2, e2y = u2y / n2, e2z = u2z / n2;
    float e3x = e1y * e2z - e1z * e2y;
    float e3y = e1z * e2x - e1x * e2z;
    float e3z = e1x * e2y - e1y * e2x;
    float* tf = tF + l * 12;
    tf[0] = e1x; tf[1] = e1y; tf[2] = e1z;
    tf[3] = e2x; tf[4] = e2y; tf[5] = e2z;
    tf[6] = e3x; tf[7] = e3y; tf[8] = e3z;
    tf[9] = x2x; tf[10] = x2y; tf[11] = x2z;
}

__device__ inline void merge_frames(const float* __restrict__ A, const float* __restrict__ B,
                                    float* __restrict__ out) {
    const float* RA = A; const float* OA = A + 9;
    const float* RB = B; const float* OB = B + 9;
    bool close = (fabsf(OA[0] - OB[0]) <= ATOLV + RTOLV * fabsf(OB[0])) &&
                 (fabsf(OA[1] - OB[1]) <= ATOLV + RTOLV * fabsf(OB[1])) &&
                 (fabsf(OA[2] - OB[2]) <= ATOLV + RTOLV * fabsf(OB[2]));
    float d0 = OB[0] - OA[0], d1 = OB[1] - OA[1], d2 = OB[2] - OA[2];
    float nd = sqrtf(d0 * d0 + d1 * d1 + d2 * d2);
    float nds = (nd == 0.f) ? 1.f : nd;
    float X0 = d0 / nds, X1 = d1 / nds, X2 = d2 / nds;
    float Za0 = RA[6] + RB[6], Za1 = RA[7] + RB[7], Za2 = RA[8] + RB[8];
    float Zs0 = RA[6] - RB[6], Zs1 = RA[7] - RB[7], Zs2 = RA[8] - RB[8];
    float na = sqrtf(Za0 * Za0 + Za1 * Za1 + Za2 * Za2);
    float ns = sqrtf(Zs0 * Zs0 + Zs1 * Zs1 + Zs2 * Zs2);
    float nas = (na == 0.f) ? 1.f : na;
    float nss = (ns == 0.f) ? 1.f : ns;
    float Z0, Z1, Z2;
    if (na > ns) { Z0 = Za0 / nas; Z1 = Za1 / nas; Z2 = Za2 / nas; }
    else         { Z0 = Zs0 / nss; Z1 = Zs1 / nss; Z2 = Zs2 / nss; }
    float Y0 = Z1 * X2 - Z2 * X1;
    float Y1 = Z2 * X0 - Z0 * X2;
    float Y2 = Z0 * X1 - Z1 * X0;
    bool nanbad = (Y0 != Y0) || (Y1 != Y1) || (Y2 != Y2);
    float C0 = X1 * Y2 - X2 * Y1;
    float C1 = X2 * Y0 - X0 * Y2;
    float C2 = X0 * Y1 - X1 * Y0;
    float dotv = C0 * Z0 + C1 * Z1 + C2 * Z2;
    if (dotv < 0.f) { Y0 = -Y0; Y1 = -Y1; Y2 = -Y2; }
    bool bad = close || (nd == 0.f) || (na == 0.f) || (ns == 0.f) || nanbad;
    if (bad) {
#pragma unroll
        for (int k = 0; k < 12; k++) out[k] = A[k];
    } else {
        out[0] = X0; out[1] = X1; out[2] = X2;
        out[3] = Y0; out[4] = Y1; out[5] = Y2;
        out[6] = Z0; out[7] = Z1; out[8] = Z2;
        out[9]  = 0.5f * (OA[0] + OB[0]);
        out[10] = 0.5f * (OA[1] + OB[1]);
        out[11] = 0.5f * (OA[2] + OB[2]);
    }
}

__global__ void k_merge(const int2* __restrict__ pairs, const unsigned int* __restrict__ count,
                        int cap, int L, float* __restrict__ pF, float* __restrict__ tF) {
    int p = blockIdx.x * 256 + threadIdx.x;
    unsigned int cnt = *count;
    if (cnt > (unsigned int)cap) cnt = (unsigned int)cap;
    if (p >= (int)cnt) return;
    int2 ij = pairs[p];
    merge_frames(pF + ij.x * 12, pF + ij.y * 12, pF + (size_t)(L + p) * 12);
    merge_frames(tF + ij.x * 12, tF + ij.y * 12, tF + (size_t)(L + p) * 12);
}

// Persistent grid-stride over (frame-block, point-chunk) work items; runtime-exact
// chunk count (no dead blocks). Points staged as padded float4 (broadcast b128 reads).
// Per-frame constant k = R_T*t_T - R_P*t_P folds both translations.
__global__ __launch_bounds__(256)
void k_main(const float* __restrict__ coor, const float* __restrict__ target,
            const float* __restrict__ pF, const float* __restrict__ tF,
            const unsigned int* __restrict__ count, int cap, int L, int Npts,
            double* __restrict__ acc) {
    __shared__ float4 sC[CHUNK];
    __shared__ float4 sT[CHUNK];
    __shared__ float sRed[4];
    unsigned int cnt = *count;
    if (cnt > (unsigned int)cap) cnt = (unsigned int)cap;
    int F = L + (int)cnt;
    int nfb = (F + 255) >> 8;
    int nyc = (Npts + CHUNK - 1) / CHUNK;
    int total = nfb * nyc;
    float a0 = 0.f, a1 = 0.f;

    for (int chunk = blockIdx.x; chunk < total; chunk += gridDim.x) {
        int fb = chunk % nfb;
        int yc = chunk / nfb;
        int n0 = yc * CHUNK;
        int npts = Npts - n0; if (npts > CHUNK) npts = CHUNK;
        __syncthreads();   // protect LDS reuse across grid-stride iterations
        for (int idx = threadIdx.x; idx < npts; idx += 256) {
            int g = (n0 + idx) * 3;
            sC[idx] = make_float4(coor[g], coor[g + 1], coor[g + 2], 0.f);
            sT[idx] = make_float4(target[g], target[g + 1], target[g + 2], 0.f);
        }
        __syncthreads();
        int f = fb * 256 + threadIdx.x;
        if (f >= F) continue;   // per-lane; block-uniform ops above/below unaffected

        const float4* pf4 = (const float4*)(pF + (size_t)f * 12);
        const float4* tf4 = (const float4*)(tF + (size_t)f * 12);
        float4 p0 = pf4[0], p1 = pf4[1], p2 = pf4[2];
        float4 t0 = tf4[0], t1 = tf4[1], t2 = tf4[2];
        // P rows: (p0.x p0.y p0.z) (p0.w p1.x p1.y) (p1.z p1.w p2.x); tP = (p2.y p2.z p2.w)
        float P00 = p0.x, P01 = p0.y, P02 = p0.z;
        float P10 = p0.w, P11 = p1.x, P12 = p1.y;
        float P20 = p1.z, P21 = p1.w, P22 = p2.x;
        float tPx = p2.y, tPy = p2.z, tPz = p2.w;
        float T00 = t0.x, T01 = t0.y, T02 = t0.z;
        float T10 = t0.w, T11 = t1.x, T12 = t1.y;
        float T20 = t1.z, T21 = t1.w, T22 = t2.x;
        float tTx = t2.y, tTy = t2.z, tTz = t2.w;
        // k = R_T*t_T - R_P*t_P
        float kx = T00 * tTx + T01 * tTy + T02 * tTz - (P00 * tPx + P01 * tPy + P02 * tPz);
        float ky = T10 * tTx + T11 * tTy + T12 * tTz - (P10 * tPx + P11 * tPy + P12 * tPz);
        float kz = T20 * tTx + T21 * tTy + T22 * tTz - (P20 * tPx + P21 * tPy + P22 * tPz);
        // negate T rows once so inner loop is all positive FMAs
        float N00 = -T00, N01 = -T01, N02 = -T02;
        float N10 = -T10, N11 = -T11, N12 = -T12;
        float N20 = -T20, N21 = -T21, N22 = -T22;

#pragma unroll 4
        for (int n = 0; n < npts; n++) {
            float4 c = sC[n];
            float4 t = sT[n];
            float ux = kx + P00 * c.x + P01 * c.y + P02 * c.z
                          + N00 * t.x + N01 * t.y + N02 * t.z;
            float uy = ky + P10 * c.x + P11 * c.y + P12 * c.z
                          + N10 * t.x + N11 * t.y + N12 * t.z;
            float uz = kz + P20 * c.x + P21 * c.y + P22 * c.z
                          + N20 * t.x + N21 * t.y + N22 * t.z;
            float s = ux * ux + uy * uy + uz * uz + 3.0f * EPV;
            float r = fminf(sqrtf(s), EPMAXV);
            if (n & 1) a1 += r; else a0 += r;
        }
    }

    float a = a0 + a1;
#pragma unroll
    for (int off = 32; off > 0; off >>= 1) a += __shfl_down(a, off, 64);
    int lane = threadIdx.x & 63, wv = threadIdx.x >> 6;
    __syncthreads();
    if (lane == 0) sRed[wv] = a;
    __syncthreads();
    if (threadIdx.x == 0) {
        float s = sRed[0] + sRed[1] + sRed[2] + sRed[3];
        atomicAdd(acc, (double)s);
    }
}

__global__ void k_final(const double* __restrict__ acc, const unsigned int* __restrict__ count,
                        int cap, int L, int Npts, float* __restrict__ out) {
    unsigned int cnt = *count;
    if (cnt > (unsigned int)cap) cnt = (unsigned int)cap;
    double F = (double)(L + (int)cnt);
    out[0] = (float)(*acc / ((double)Npts * F));
}

extern "C" void kernel_launch(void* const* d_in, const int* in_sizes, int n_in,
                              void* d_out, int out_size, void* d_ws, size_t ws_size,
                              hipStream_t stream) {
    const float* coor   = (const float*)d_in[0];
    const float* rot    = (const float*)d_in[1];
    const float* trans  = (const float*)d_in[2];
    const float* target = (const float*)d_in[3];
    const int*   matrix = (const int*)d_in[4];
    int L    = in_sizes[2] / 3;     // trans has L*3 elements
    int Npts = 3 * L;

    char* ws = (char*)d_ws;
    double*       acc   = (double*)ws;
    unsigned int* count = (unsigned int*)(ws + 8);
    // need(cap) = 16 + 8*cap + 96*(L+cap) bytes
    long cap_ws = ((long)ws_size - 16 - 96L * (long)L) / 104;
    long capl = cap_ws < 32768 ? cap_ws : 32768;
    if (capl < 0) capl = 0;
    int cap = (int)(capl & ~1L);    // even -> frames stay 16B-aligned
    int2*  pairs = (int2*)(ws + 16);
    float* pF = (float*)(ws + 16 + (size_t)cap * 8);
    float* tF = pF + (size_t)(L + cap) * 12;

    hipMemsetAsync(ws, 0, 16, stream);
    k_pairs<<<L, 256, 0, stream>>>(matrix, L, pairs, count, cap);
    k_base<<<(L + 255) / 256, 256, 0, stream>>>(rot, trans, target, L, pF, tF);
    if (cap > 0)
        k_merge<<<(cap + 255) / 256, 256, 0, stream>>>(pairs, count, cap, L, pF, tF);
    k_main<<<MAIN_GRID, 256, 0, stream>>>(coor, target, pF, tF, count, cap, L, Npts, acc);
    k_final<<<1, 1, 0, stream>>>(acc, count, cap, L, Npts, (float*)d_out);
}

// Round 3
// 122.455 us; speedup vs baseline: 1.2953x; 1.2953x over previous
//
#include <hip/hip_runtime.h>

#define EPV    0.0001f
#define EPMAXV 30.0f
#define RTOLV  1e-5f
#define ATOLV  1e-8f
#define CHUNK  64
#define NPART  1024   // k_main grid size == number of partial sums

// ---------------------------------------------------------------------------
// ws layout (all offsets computed on host, 16B-aligned sections):
//   [8,12)              uint count            (written by k_scan)
//   rowcnt[L]  uint
//   rowoff[L]  uint
//   partials[NPART] double
//   pairs[cap] int2
//   pF[(L+cap)*12] float   (pred frames: 3x3 rot rows + tran)
//   tF[(L+cap)*12] float   (target frames)
// ---------------------------------------------------------------------------

// wave-per-row: count upper-triangular ones via ballot (no atomics)
__global__ void k_rowcnt(const int* __restrict__ m, int L, unsigned int* __restrict__ rowcnt) {
    int i = blockIdx.x * 4 + (threadIdx.x >> 6);
    if (i >= L) return;
    int lane = threadIdx.x & 63;
    const int* row = m + (size_t)i * L;
    unsigned int c = 0;
    for (int j0 = 0; j0 < L; j0 += 64) {
        int j = j0 + lane;
        bool v = (j < L) && (j > i) && (row[j] == 1);
        unsigned long long b = __ballot(v);
        c += (unsigned int)__popcll(b);
    }
    if (lane == 0) rowcnt[i] = c;
}

// single-block exclusive scan over rowcnt -> rowoff, total -> count
__global__ void k_scan(const unsigned int* __restrict__ rowcnt, int L,
                       unsigned int* __restrict__ rowoff, unsigned int* __restrict__ count) {
    __shared__ unsigned int s[256];
    unsigned int carry = 0;
    for (int base = 0; base < L; base += 256) {
        int idx = base + threadIdx.x;
        unsigned int v = (idx < L) ? rowcnt[idx] : 0u;
        s[threadIdx.x] = v;
        __syncthreads();
        for (int off = 1; off < 256; off <<= 1) {
            unsigned int t = (threadIdx.x >= (unsigned)off) ? s[threadIdx.x - off] : 0u;
            __syncthreads();
            s[threadIdx.x] += t;
            __syncthreads();
        }
        if (idx < L) rowoff[idx] = carry + s[threadIdx.x] - v;   // exclusive
        carry += s[255];
        __syncthreads();
    }
    if (threadIdx.x == 0) *count = carry;
}

// wave-per-row: emit pairs at rowoff[i] + ballot-prefix position (no atomics)
__global__ void k_fill(const int* __restrict__ m, int L, const unsigned int* __restrict__ rowoff,
                       int2* __restrict__ pairs, int cap) {
    int i = blockIdx.x * 4 + (threadIdx.x >> 6);
    if (i >= L) return;
    int lane = threadIdx.x & 63;
    const int* row = m + (size_t)i * L;
    unsigned int base = rowoff[i];
    unsigned long long lt = (lane == 0) ? 0ull : ((1ull << lane) - 1ull);
    for (int j0 = 0; j0 < L; j0 += 64) {
        int j = j0 + lane;
        bool v = (j < L) && (j > i) && (row[j] == 1);
        unsigned long long b = __ballot(v);
        if (v) {
            unsigned int pos = base + (unsigned int)__popcll(b & lt);
            if (pos < (unsigned int)cap) pairs[pos] = make_int2(i, j);
        }
        base += (unsigned int)__popcll(b);
    }
}

__global__ void k_base(const float* __restrict__ rot, const float* __restrict__ trans,
                       const float* __restrict__ target, int L,
                       float* __restrict__ pF, float* __restrict__ tF) {
    int l = blockIdx.x * 256 + threadIdx.x;
    if (l >= L) return;
    float* pf = pF + l * 12;
#pragma unroll
    for (int k = 0; k < 9; k++) pf[k] = rot[l * 9 + k];
    pf[9]  = trans[l * 3 + 0];
    pf[10] = trans[l * 3 + 1];
    pf[11] = trans[l * 3 + 2];
    const float* tg = target + l * 9;
    float x1x = tg[0], x1y = tg[1], x1z = tg[2];
    float x2x = tg[3], x2y = tg[4], x2z = tg[5];
    float x3x = tg[6], x3y = tg[7], x3z = tg[8];
    float v1x = x3x - x2x, v1y = x3y - x2y, v1z = x3z - x2z;
    float v2x = x1x - x2x, v2y = x1y - x2y, v2z = x1z - x2z;
    float n1 = sqrtf(v1x * v1x + v1y * v1y + v1z * v1z) + 0.001f;
    float e1x = v1x / n1, e1y = v1y / n1, e1z = v1z / n1;
    float c = e1x * v2x + e1y * v2y + e1z * v2z;
    float u2x = v2x - c * e1x, u2y = v2y - c * e1y, u2z = v2z - c * e1z;
    float n2 = sqrtf(u2x * u2x + u2y * u2y + u2z * u2z) + 1e-8f;
    float e2x = u2x / n2, e2y = u2y / n2, e2z = u2z / n2;
    float e3x = e1y * e2z - e1z * e2y;
    float e3y = e1z * e2x - e1x * e2z;
    float e3z = e1x * e2y - e1y * e2x;
    float* tf = tF + l * 12;
    tf[0] = e1x; tf[1] = e1y; tf[2] = e1z;
    tf[3] = e2x; tf[4] = e2y; tf[5] = e2z;
    tf[6] = e3x; tf[7] = e3y; tf[8] = e3z;
    tf[9] = x2x; tf[10] = x2y; tf[11] = x2z;
}

__device__ inline void merge_frames(const float* __restrict__ A, const float* __restrict__ B,
                                    float* __restrict__ out) {
    const float* RA = A; const float* OA = A + 9;
    const float* RB = B; const float* OB = B + 9;
    bool close = (fabsf(OA[0] - OB[0]) <= ATOLV + RTOLV * fabsf(OB[0])) &&
                 (fabsf(OA[1] - OB[1]) <= ATOLV + RTOLV * fabsf(OB[1])) &&
                 (fabsf(OA[2] - OB[2]) <= ATOLV + RTOLV * fabsf(OB[2]));
    float d0 = OB[0] - OA[0], d1 = OB[1] - OA[1], d2 = OB[2] - OA[2];
    float nd = sqrtf(d0 * d0 + d1 * d1 + d2 * d2);
    float nds = (nd == 0.f) ? 1.f : nd;
    float X0 = d0 / nds, X1 = d1 / nds, X2 = d2 / nds;
    float Za0 = RA[6] + RB[6], Za1 = RA[7] + RB[7], Za2 = RA[8] + RB[8];
    float Zs0 = RA[6] - RB[6], Zs1 = RA[7] - RB[7], Zs2 = RA[8] - RB[8];
    float na = sqrtf(Za0 * Za0 + Za1 * Za1 + Za2 * Za2);
    float ns = sqrtf(Zs0 * Zs0 + Zs1 * Zs1 + Zs2 * Zs2);
    float nas = (na == 0.f) ? 1.f : na;
    float nss = (ns == 0.f) ? 1.f : ns;
    float Z0, Z1, Z2;
    if (na > ns) { Z0 = Za0 / nas; Z1 = Za1 / nas; Z2 = Za2 / nas; }
    else         { Z0 = Zs0 / nss; Z1 = Zs1 / nss; Z2 = Zs2 / nss; }
    float Y0 = Z1 * X2 - Z2 * X1;
    float Y1 = Z2 * X0 - Z0 * X2;
    float Y2 = Z0 * X1 - Z1 * X0;
    bool nanbad = (Y0 != Y0) || (Y1 != Y1) || (Y2 != Y2);
    float C0 = X1 * Y2 - X2 * Y1;
    float C1 = X2 * Y0 - X0 * Y2;
    float C2 = X0 * Y1 - X1 * Y0;
    float dotv = C0 * Z0 + C1 * Z1 + C2 * Z2;
    if (dotv < 0.f) { Y0 = -Y0; Y1 = -Y1; Y2 = -Y2; }
    bool bad = close || (nd == 0.f) || (na == 0.f) || (ns == 0.f) || nanbad;
    if (bad) {
#pragma unroll
        for (int k = 0; k < 12; k++) out[k] = A[k];
    } else {
        out[0] = X0; out[1] = X1; out[2] = X2;
        out[3] = Y0; out[4] = Y1; out[5] = Y2;
        out[6] = Z0; out[7] = Z1; out[8] = Z2;
        out[9]  = 0.5f * (OA[0] + OB[0]);
        out[10] = 0.5f * (OA[1] + OB[1]);
        out[11] = 0.5f * (OA[2] + OB[2]);
    }
}

__global__ void k_merge(const int2* __restrict__ pairs, const unsigned int* __restrict__ count,
                        int cap, int L, float* __restrict__ pF, float* __restrict__ tF) {
    int p = blockIdx.x * 256 + threadIdx.x;
    unsigned int cnt = *count;
    if (cnt > (unsigned int)cap) cnt = (unsigned int)cap;
    if (p >= (int)cnt) return;
    int2 ij = pairs[p];
    merge_frames(pF + ij.x * 12, pF + ij.y * 12, pF + (size_t)(L + p) * 12);
    merge_frames(tF + ij.x * 12, tF + ij.y * 12, tF + (size_t)(L + p) * 12);
}

// Persistent grid-stride over (frame-block, point-chunk) work items. Points staged
// as padded float4. Per-frame constant k = R_T*t_T - R_P*t_P folds translations.
// Block partial -> partials[blockIdx.x] (no atomics).
__global__ __launch_bounds__(256)
void k_main(const float* __restrict__ coor, const float* __restrict__ target,
            const float* __restrict__ pF, const float* __restrict__ tF,
            const unsigned int* __restrict__ count, int cap, int L, int Npts,
            double* __restrict__ partials) {
    __shared__ float4 sC[CHUNK];
    __shared__ float4 sT[CHUNK];
    __shared__ float sRed[4];
    unsigned int cnt = *count;
    if (cnt > (unsigned int)cap) cnt = (unsigned int)cap;
    int F = L + (int)cnt;
    int nfb = (F + 255) >> 8;
    int nyc = (Npts + CHUNK - 1) / CHUNK;
    int total = nfb * nyc;
    float a0 = 0.f, a1 = 0.f;

    for (int chunk = blockIdx.x; chunk < total; chunk += gridDim.x) {
        int fb = chunk % nfb;
        int yc = chunk / nfb;
        int n0 = yc * CHUNK;
        int npts = Npts - n0; if (npts > CHUNK) npts = CHUNK;
        __syncthreads();   // protect LDS reuse across grid-stride iterations
        for (int idx = threadIdx.x; idx < npts; idx += 256) {
            int g = (n0 + idx) * 3;
            sC[idx] = make_float4(coor[g], coor[g + 1], coor[g + 2], 0.f);
            sT[idx] = make_float4(target[g], target[g + 1], target[g + 2], 0.f);
        }
        __syncthreads();
        int f = fb * 256 + threadIdx.x;
        if (f >= F) continue;   // per-lane; block-uniform structure unaffected

        const float4* pf4 = (const float4*)(pF + (size_t)f * 12);
        const float4* tf4 = (const float4*)(tF + (size_t)f * 12);
        float4 p0 = pf4[0], p1 = pf4[1], p2 = pf4[2];
        float4 t0 = tf4[0], t1 = tf4[1], t2 = tf4[2];
        float P00 = p0.x, P01 = p0.y, P02 = p0.z;
        float P10 = p0.w, P11 = p1.x, P12 = p1.y;
        float P20 = p1.z, P21 = p1.w, P22 = p2.x;
        float tPx = p2.y, tPy = p2.z, tPz = p2.w;
        float T00 = t0.x, T01 = t0.y, T02 = t0.z;
        float T10 = t0.w, T11 = t1.x, T12 = t1.y;
        float T20 = t1.z, T21 = t1.w, T22 = t2.x;
        float tTx = t2.y, tTy = t2.z, tTz = t2.w;
        float kx = T00 * tTx + T01 * tTy + T02 * tTz - (P00 * tPx + P01 * tPy + P02 * tPz);
        float ky = T10 * tTx + T11 * tTy + T12 * tTz - (P10 * tPx + P11 * tPy + P12 * tPz);
        float kz = T20 * tTx + T21 * tTy + T22 * tTz - (P20 * tPx + P21 * tPy + P22 * tPz);
        float N00 = -T00, N01 = -T01, N02 = -T02;
        float N10 = -T10, N11 = -T11, N12 = -T12;
        float N20 = -T20, N21 = -T21, N22 = -T22;

#pragma unroll 4
        for (int n = 0; n < npts; n++) {
            float4 c = sC[n];
            float4 t = sT[n];
            float ux = kx + P00 * c.x + P01 * c.y + P02 * c.z
                          + N00 * t.x + N01 * t.y + N02 * t.z;
            float uy = ky + P10 * c.x + P11 * c.y + P12 * c.z
                          + N10 * t.x + N11 * t.y + N12 * t.z;
            float uz = kz + P20 * c.x + P21 * c.y + P22 * c.z
                          + N20 * t.x + N21 * t.y + N22 * t.z;
            float s = ux * ux + uy * uy + uz * uz + 3.0f * EPV;
            float r = fminf(sqrtf(s), EPMAXV);
            if (n & 1) a1 += r; else a0 += r;
        }
    }

    float a = a0 + a1;
#pragma unroll
    for (int off = 32; off > 0; off >>= 1) a += __shfl_down(a, off, 64);
    int lane = threadIdx.x & 63, wv = threadIdx.x >> 6;
    if (lane == 0) sRed[wv] = a;
    __syncthreads();
    if (threadIdx.x == 0)
        partials[blockIdx.x] = (double)(sRed[0] + sRed[1] + sRed[2] + sRed[3]);
}

__global__ void k_final(const double* __restrict__ partials, int npart,
                        const unsigned int* __restrict__ count, int cap,
                        int L, int Npts, float* __restrict__ out) {
    __shared__ double sR[4];
    double d = 0.0;
    for (int i = threadIdx.x; i < npart; i += 256) d += partials[i];
#pragma unroll
    for (int off = 32; off > 0; off >>= 1) d += __shfl_down(d, off, 64);
    int lane = threadIdx.x & 63, wv = threadIdx.x >> 6;
    if (lane == 0) sR[wv] = d;
    __syncthreads();
    if (threadIdx.x == 0) {
        double tot = sR[0] + sR[1] + sR[2] + sR[3];
        unsigned int cnt = *count;
        if (cnt > (unsigned int)cap) cnt = (unsigned int)cap;
        double F = (double)(L + (int)cnt);
        out[0] = (float)(tot / ((double)Npts * F));
    }
}

extern "C" void kernel_launch(void* const* d_in, const int* in_sizes, int n_in,
                              void* d_out, int out_size, void* d_ws, size_t ws_size,
                              hipStream_t stream) {
    const float* coor   = (const float*)d_in[0];
    const float* rot    = (const float*)d_in[1];
    const float* trans  = (const float*)d_in[2];
    const float* target = (const float*)d_in[3];
    const int*   matrix = (const int*)d_in[4];
    int L    = in_sizes[2] / 3;     // trans has L*3 elements
    int Npts = 3 * L;

    char* ws = (char*)d_ws;
    size_t off = 16;
    unsigned int* count  = (unsigned int*)(ws + 8);
    unsigned int* rowcnt = (unsigned int*)(ws + off); off += 4 * (size_t)L;
    unsigned int* rowoff = (unsigned int*)(ws + off); off += 4 * (size_t)L;
    off = (off + 15) & ~(size_t)15;
    double* partials = (double*)(ws + off); off += 8 * (size_t)NPART;
    off = (off + 15) & ~(size_t)15;
    // remaining need(cap) = 8*cap + 96*(L+cap)
    long cap_ws = ((long)ws_size - (long)off - 96L * (long)L) / 104;
    long capl = cap_ws < 32768 ? cap_ws : 32768;
    if (capl < 0) capl = 0;
    int cap = (int)(capl & ~1L);    // even -> frames stay 16B-aligned
    int2*  pairs = (int2*)(ws + off);
    float* pF = (float*)(ws + off + (size_t)cap * 8);
    float* tF = pF + (size_t)(L + cap) * 12;

    int nrb = (L + 3) / 4;   // wave-per-row blocks
    k_rowcnt<<<nrb, 256, 0, stream>>>(matrix, L, rowcnt);
    k_base<<<(L + 255) / 256, 256, 0, stream>>>(rot, trans, target, L, pF, tF);
    k_scan<<<1, 256, 0, stream>>>(rowcnt, L, rowoff, count);
    k_fill<<<nrb, 256, 0, stream>>>(matrix, L, rowoff, pairs, cap);
    if (cap > 0)
        k_merge<<<(cap + 255) / 256, 256, 0, stream>>>(pairs, count, cap, L, pF, tF);
    k_main<<<NPART, 256, 0, stream>>>(coor, target, pF, tF, count, cap, L, Npts, partials);
    k_final<<<1, 256, 0, stream>>>(partials, NPART, count, cap, L, Npts, (float*)d_out);
}

// Round 4
// 114.803 us; speedup vs baseline: 1.3816x; 1.0667x over previous
//
#include <hip/hip_runtime.h>

#define EPV    0.0001f
#define EPMAXV 30.0f
#define CHUNK  64
#define NPART  2048   // k_main grid size == number of partial sums

// ---------------------------------------------------------------------------
// ws layout (host-computed offsets, 16B-aligned sections):
//   [0,4)    uint count            (written by k_fillmerge block 0)
//   rowcnt[L]       uint
//   partials[NPART] double
//   pF[(L+cap)*12]  float   (pred frames: 3x3 rot rows + tran)
//   tF[(L+cap)*12]  float   (target frames)
// ---------------------------------------------------------------------------

// Fused: blocks [0, nrb) do wave-per-row popcount of strict-upper ones;
// blocks [nrb, nrb+nbase) build base frames (copy pred, rigid_from_3 target).
__global__ void k_prep(const int* __restrict__ m, int L, unsigned int* __restrict__ rowcnt,
                       const float* __restrict__ rot, const float* __restrict__ trans,
                       const float* __restrict__ target, int nrb,
                       float* __restrict__ pF, float* __restrict__ tF) {
    if ((int)blockIdx.x < nrb) {
        int i = blockIdx.x * 4 + (threadIdx.x >> 6);
        if (i >= L) return;
        int lane = threadIdx.x & 63;
        const int* row = m + (size_t)i * L;
        unsigned int c = 0;
        for (int j0 = 0; j0 < L; j0 += 64) {
            int j = j0 + lane;
            bool v = (j < L) && (j > i) && (row[j] == 1);
            unsigned long long b = __ballot(v);
            c += (unsigned int)__popcll(b);
        }
        if (lane == 0) rowcnt[i] = c;
        return;
    }
    int l = ((int)blockIdx.x - nrb) * 256 + threadIdx.x;
    if (l >= L) return;
    float* pf = pF + l * 12;
#pragma unroll
    for (int k = 0; k < 9; k++) pf[k] = rot[l * 9 + k];
    pf[9]  = trans[l * 3 + 0];
    pf[10] = trans[l * 3 + 1];
    pf[11] = trans[l * 3 + 2];
    const float* tg = target + l * 9;
    float x1x = tg[0], x1y = tg[1], x1z = tg[2];
    float x2x = tg[3], x2y = tg[4], x2z = tg[5];
    float x3x = tg[6], x3y = tg[7], x3z = tg[8];
    float v1x = x3x - x2x, v1y = x3y - x2y, v1z = x3z - x2z;
    float v2x = x1x - x2x, v2y = x1y - x2y, v2z = x1z - x2z;
    float n1 = sqrtf(v1x * v1x + v1y * v1y + v1z * v1z) + 0.001f;
    float e1x = v1x / n1, e1y = v1y / n1, e1z = v1z / n1;
    float c = e1x * v2x + e1y * v2y + e1z * v2z;
    float u2x = v2x - c * e1x, u2y = v2y - c * e1y, u2z = v2z - c * e1z;
    float n2 = sqrtf(u2x * u2x + u2y * u2y + u2z * u2z) + 1e-8f;
    float e2x = u2x / n2, e2y = u2y / n2, e2z = u2z / n2;
    float e3x = e1y * e2z - e1z * e2y;
    float e3y = e1z * e2x - e1x * e2z;
    float e3z = e1x * e2y - e1y * e2x;
    float* tf = tF + l * 12;
    tf[0] = e1x; tf[1] = e1y; tf[2] = e1z;
    tf[3] = e2x; tf[4] = e2y; tf[5] = e2z;
    tf[6] = e3x; tf[7] = e3y; tf[8] = e3z;
    tf[9] = x2x; tf[10] = x2y; tf[11] = x2z;
}

#define RTOLV  1e-5f
#define ATOLV  1e-8f

__device__ inline void merge_frames(const float* __restrict__ A, const float* __restrict__ B,
                                    float* __restrict__ out) {
    const float* RA = A; const float* OA = A + 9;
    const float* RB = B; const float* OB = B + 9;
    bool close = (fabsf(OA[0] - OB[0]) <= ATOLV + RTOLV * fabsf(OB[0])) &&
                 (fabsf(OA[1] - OB[1]) <= ATOLV + RTOLV * fabsf(OB[1])) &&
                 (fabsf(OA[2] - OB[2]) <= ATOLV + RTOLV * fabsf(OB[2]));
    float d0 = OB[0] - OA[0], d1 = OB[1] - OA[1], d2 = OB[2] - OA[2];
    float nd = sqrtf(d0 * d0 + d1 * d1 + d2 * d2);
    float nds = (nd == 0.f) ? 1.f : nd;
    float X0 = d0 / nds, X1 = d1 / nds, X2 = d2 / nds;
    float Za0 = RA[6] + RB[6], Za1 = RA[7] + RB[7], Za2 = RA[8] + RB[8];
    float Zs0 = RA[6] - RB[6], Zs1 = RA[7] - RB[7], Zs2 = RA[8] - RB[8];
    float na = sqrtf(Za0 * Za0 + Za1 * Za1 + Za2 * Za2);
    float ns = sqrtf(Zs0 * Zs0 + Zs1 * Zs1 + Zs2 * Zs2);
    float nas = (na == 0.f) ? 1.f : na;
    float nss = (ns == 0.f) ? 1.f : ns;
    float Z0, Z1, Z2;
    if (na > ns) { Z0 = Za0 / nas; Z1 = Za1 / nas; Z2 = Za2 / nas; }
    else         { Z0 = Zs0 / nss; Z1 = Zs1 / nss; Z2 = Zs2 / nss; }
    float Y0 = Z1 * X2 - Z2 * X1;
    float Y1 = Z2 * X0 - Z0 * X2;
    float Y2 = Z0 * X1 - Z1 * X0;
    bool nanbad = (Y0 != Y0) || (Y1 != Y1) || (Y2 != Y2);
    float C0 = X1 * Y2 - X2 * Y1;
    float C1 = X2 * Y0 - X0 * Y2;
    float C2 = X0 * Y1 - X1 * Y0;
    float dotv = C0 * Z0 + C1 * Z1 + C2 * Z2;
    if (dotv < 0.f) { Y0 = -Y0; Y1 = -Y1; Y2 = -Y2; }
    bool bad = close || (nd == 0.f) || (na == 0.f) || (ns == 0.f) || nanbad;
    if (bad) {
#pragma unroll
        for (int k = 0; k < 12; k++) out[k] = A[k];
    } else {
        out[0] = X0; out[1] = X1; out[2] = X2;
        out[3] = Y0; out[4] = Y1; out[5] = Y2;
        out[6] = Z0; out[7] = Z1; out[8] = Z2;
        out[9]  = 0.5f * (OA[0] + OB[0]);
        out[10] = 0.5f * (OA[1] + OB[1]);
        out[11] = 0.5f * (OA[2] + OB[2]);
    }
}

// Fused fill+merge: wave-per-row. Each wave redundantly computes its row's
// exclusive prefix from rowcnt (L2-resident), re-scans the row, and for each
// found pair directly merges pred+target frames into pF/tF[L+pos].
// Block 0 wave 0 also writes the total pair count. No atomics, no pair list.
__global__ void k_fillmerge(const int* __restrict__ m, int L,
                            const unsigned int* __restrict__ rowcnt,
                            unsigned int* __restrict__ count, int cap,
                            float* __restrict__ pF, float* __restrict__ tF) {
    int i = blockIdx.x * 4 + (threadIdx.x >> 6);
    int lane = threadIdx.x & 63;

    if (blockIdx.x == 0 && (threadIdx.x >> 6) == 0) {
        // wave 0 of block 0: total count (full reduction over rowcnt)
        unsigned int t = 0;
        for (int r = lane; r < L; r += 64) t += rowcnt[r];
#pragma unroll
        for (int off = 1; off < 64; off <<= 1) t += __shfl_xor(t, off, 64);
        if (lane == 0) *count = t;
    }
    if (i >= L) return;

    // exclusive prefix for row i
    unsigned int p = 0;
    for (int r = lane; r < i; r += 64) p += rowcnt[r];
#pragma unroll
    for (int off = 1; off < 64; off <<= 1) p += __shfl_xor(p, off, 64);
    unsigned int base = p;   // all lanes hold the same value

    const int* row = m + (size_t)i * L;
    unsigned long long lt = (lane == 0) ? 0ull : ((1ull << lane) - 1ull);
    for (int j0 = 0; j0 < L; j0 += 64) {
        int j = j0 + lane;
        bool v = (j < L) && (j > i) && (row[j] == 1);
        unsigned long long b = __ballot(v);
        if (v) {
            unsigned int pos = base + (unsigned int)__popcll(b & lt);
            if (pos < (unsigned int)cap) {
                merge_frames(pF + i * 12, pF + j * 12, pF + (size_t)(L + pos) * 12);
                merge_frames(tF + i * 12, tF + j * 12, tF + (size_t)(L + pos) * 12);
            }
        }
        base += (unsigned int)__popcll(b);
    }
}

// Persistent grid-stride over (frame-block, point-chunk) chunks; grid = NPART so
// each block handles at most one chunk for this problem size (balanced CUs).
// Points staged as padded float4 (broadcast ds_read_b128). Per-frame constant
// k = R_T*t_T - R_P*t_P folds translations. Block partial -> partials[blockIdx.x].
__global__ __launch_bounds__(256)
void k_main(const float* __restrict__ coor, const float* __restrict__ target,
            const float* __restrict__ pF, const float* __restrict__ tF,
            const unsigned int* __restrict__ count, int cap, int L, int Npts,
            double* __restrict__ partials) {
    __shared__ float4 sC[CHUNK];
    __shared__ float4 sT[CHUNK];
    __shared__ float sRed[4];
    unsigned int cnt = *count;
    if (cnt > (unsigned int)cap) cnt = (unsigned int)cap;
    int F = L + (int)cnt;
    int nfb = (F + 255) >> 8;
    int nyc = (Npts + CHUNK - 1) / CHUNK;
    int total = nfb * nyc;
    float a0 = 0.f, a1 = 0.f;

    for (int chunk = blockIdx.x; chunk < total; chunk += gridDim.x) {
        int fb = chunk % nfb;
        int yc = chunk / nfb;
        int n0 = yc * CHUNK;
        int npts = Npts - n0; if (npts > CHUNK) npts = CHUNK;
        __syncthreads();   // protect LDS reuse across grid-stride iterations
        for (int idx = threadIdx.x; idx < npts; idx += 256) {
            int g = (n0 + idx) * 3;
            sC[idx] = make_float4(coor[g], coor[g + 1], coor[g + 2], 0.f);
            sT[idx] = make_float4(target[g], target[g + 1], target[g + 2], 0.f);
        }
        __syncthreads();
        int f = fb * 256 + threadIdx.x;
        if (f >= F) continue;   // per-lane; block-uniform structure unaffected

        const float4* pf4 = (const float4*)(pF + (size_t)f * 12);
        const float4* tf4 = (const float4*)(tF + (size_t)f * 12);
        float4 p0 = pf4[0], p1 = pf4[1], p2 = pf4[2];
        float4 t0 = tf4[0], t1 = tf4[1], t2 = tf4[2];
        float P00 = p0.x, P01 = p0.y, P02 = p0.z;
        float P10 = p0.w, P11 = p1.x, P12 = p1.y;
        float P20 = p1.z, P21 = p1.w, P22 = p2.x;
        float tPx = p2.y, tPy = p2.z, tPz = p2.w;
        float T00 = t0.x, T01 = t0.y, T02 = t0.z;
        float T10 = t0.w, T11 = t1.x, T12 = t1.y;
        float T20 = t1.z, T21 = t1.w, T22 = t2.x;
        float tTx = t2.y, tTy = t2.z, tTz = t2.w;
        float kx = T00 * tTx + T01 * tTy + T02 * tTz - (P00 * tPx + P01 * tPy + P02 * tPz);
        float ky = T10 * tTx + T11 * tTy + T12 * tTz - (P10 * tPx + P11 * tPy + P12 * tPz);
        float kz = T20 * tTx + T21 * tTy + T22 * tTz - (P20 * tPx + P21 * tPy + P22 * tPz);
        float N00 = -T00, N01 = -T01, N02 = -T02;
        float N10 = -T10, N11 = -T11, N12 = -T12;
        float N20 = -T20, N21 = -T21, N22 = -T22;

#pragma unroll 4
        for (int n = 0; n < npts; n++) {
            float4 c = sC[n];
            float4 t = sT[n];
            float ux = kx + P00 * c.x + P01 * c.y + P02 * c.z
                          + N00 * t.x + N01 * t.y + N02 * t.z;
            float uy = ky + P10 * c.x + P11 * c.y + P12 * c.z
                          + N10 * t.x + N11 * t.y + N12 * t.z;
            float uz = kz + P20 * c.x + P21 * c.y + P22 * c.z
                          + N20 * t.x + N21 * t.y + N22 * t.z;
            float s = ux * ux + uy * uy + uz * uz + 3.0f * EPV;
            float r = fminf(sqrtf(s), EPMAXV);
            if (n & 1) a1 += r; else a0 += r;
        }
    }

    float a = a0 + a1;
#pragma unroll
    for (int off = 32; off > 0; off >>= 1) a += __shfl_down(a, off, 64);
    int lane = threadIdx.x & 63, wv = threadIdx.x >> 6;
    if (lane == 0) sRed[wv] = a;
    __syncthreads();
    if (threadIdx.x == 0)
        partials[blockIdx.x] = (double)(sRed[0] + sRed[1] + sRed[2] + sRed[3]);
}

__global__ void k_final(const double* __restrict__ partials, int npart,
                        const unsigned int* __restrict__ count, int cap,
                        int L, int Npts, float* __restrict__ out) {
    __shared__ double sR[4];
    double d = 0.0;
    for (int i = threadIdx.x; i < npart; i += 256) d += partials[i];
#pragma unroll
    for (int off = 32; off > 0; off >>= 1) d += __shfl_down(d, off, 64);
    int lane = threadIdx.x & 63, wv = threadIdx.x >> 6;
    if (lane == 0) sR[wv] = d;
    __syncthreads();
    if (threadIdx.x == 0) {
        double tot = sR[0] + sR[1] + sR[2] + sR[3];
        unsigned int cnt = *count;
        if (cnt > (unsigned int)cap) cnt = (unsigned int)cap;
        double F = (double)(L + (int)cnt);
        out[0] = (float)(tot / ((double)Npts * F));
    }
}

extern "C" void kernel_launch(void* const* d_in, const int* in_sizes, int n_in,
                              void* d_out, int out_size, void* d_ws, size_t ws_size,
                              hipStream_t stream) {
    const float* coor   = (const float*)d_in[0];
    const float* rot    = (const float*)d_in[1];
    const float* trans  = (const float*)d_in[2];
    const float* target = (const float*)d_in[3];
    const int*   matrix = (const int*)d_in[4];
    int L    = in_sizes[2] / 3;     // trans has L*3 elements
    int Npts = 3 * L;

    char* ws = (char*)d_ws;
    size_t off = 16;
    unsigned int* count  = (unsigned int*)ws;
    unsigned int* rowcnt = (unsigned int*)(ws + off); off += 4 * (size_t)L;
    off = (off + 15) & ~(size_t)15;
    double* partials = (double*)(ws + off); off += 8 * (size_t)NPART;
    off = (off + 15) & ~(size_t)15;
    // remaining need(cap) = 96*(L+cap)
    long cap_ws = ((long)ws_size - (long)off - 96L * (long)L) / 96;
    long capl = cap_ws < 32768 ? cap_ws : 32768;
    if (capl < 0) capl = 0;
    int cap = (int)(capl & ~1L);    // even -> frames stay 16B-aligned
    float* pF = (float*)(ws + off);
    float* tF = pF + (size_t)(L + cap) * 12;

    int nrb   = (L + 3) / 4;       // wave-per-row blocks
    int nbase = (L + 255) / 256;
    k_prep<<<nrb + nbase, 256, 0, stream>>>(matrix, L, rowcnt, rot, trans, target,
                                            nrb, pF, tF);
    k_fillmerge<<<nrb, 256, 0, stream>>>(matrix, L, rowcnt, count, cap, pF, tF);
    k_main<<<NPART, 256, 0, stream>>>(coor, target, pF, tF, count, cap, L, Npts, partials);
    k_final<<<1, 256, 0, stream>>>(partials, NPART, count, cap, L, Npts, (float*)d_out);
}